// Round 1
// baseline (385.512 us; speedup 1.0000x reference)
//
#include <hip/hip_runtime.h>

#define NSEQ 1024
#define CA   768
#define CZ   128
#define NH   16
#define CHD  48
#define HC   768
#define INV_SQRT_CH 0.14433756729740643f

typedef float v4f __attribute__((ext_vector_type(4)));
typedef short v8s __attribute__((ext_vector_type(8)));

__device__ __forceinline__ short f2bf(float f) {
  union { float f; unsigned u; } v; v.f = f;
  unsigned r = v.u + 0x7fffu + ((v.u >> 16) & 1u);
  return (short)(r >> 16);
}
__device__ __forceinline__ float bf2f(short s) {
  union { unsigned u; float f; } v;
  v.u = ((unsigned)(unsigned short)s) << 16;
  return v.f;
}
__device__ __forceinline__ unsigned pack2(float a, float b) {
  return (unsigned)(unsigned short)f2bf(a) |
         ((unsigned)(unsigned short)f2bf(b) << 16);
}

// ---------------- K0: precompute wW fragments + S1/bW for z-pass ----------------
__global__ __launch_bounds__(256) void k0_prep(
    const float* __restrict__ lnw, const float* __restrict__ lnb,
    const float* __restrict__ Wb, short* __restrict__ wWp,
    float* __restrict__ S1bW)
{
  const int t = threadIdx.x;
  const int s = t >> 6, l = t & 63;
  const int r16 = l & 15, cg = l >> 4;
  float v[8];
  #pragma unroll
  for (int j = 0; j < 8; ++j) {
    int d = s * 32 + cg * 8 + j;
    v[j] = lnw[d] * Wb[d * NH + r16];
  }
  uint4 pk;
  pk.x = pack2(v[0], v[1]); pk.y = pack2(v[2], v[3]);
  pk.z = pack2(v[4], v[5]); pk.w = pack2(v[6], v[7]);
  *(uint4*)(wWp + (s * 64 + l) * 8) = pk;
  if (t < NH) {
    float s1 = 0.f, bw = 0.f;
    for (int d = 0; d < CZ; ++d) {
      float wb = Wb[d * NH + t];
      s1 += bf2f(f2bf(lnw[d] * wb));
      bw += lnb[d] * wb;
    }
    S1bW[t] = s1;
    S1bW[NH + t] = bw;
  }
}

// ---------------- K1: LayerNorm(a) -> an (fp32) ----------------
__global__ __launch_bounds__(256) void k1_ln_a(
    const float* __restrict__ a, const float* __restrict__ lnw,
    const float* __restrict__ lnb, float* __restrict__ an)
{
  const int row = blockIdx.x;
  const int tid = threadIdx.x;
  const float* ar = a + (size_t)row * CA;
  float x[3];
  float s = 0.f, s2 = 0.f;
  #pragma unroll
  for (int i = 0; i < 3; ++i) {
    x[i] = ar[tid + i * 256];
    s += x[i]; s2 += x[i] * x[i];
  }
  #pragma unroll
  for (int off = 1; off < 64; off <<= 1) {
    s += __shfl_xor(s, off);
    s2 += __shfl_xor(s2, off);
  }
  __shared__ float red[8];
  const int wv = tid >> 6;
  if ((tid & 63) == 0) { red[wv] = s; red[4 + wv] = s2; }
  __syncthreads();
  s = red[0] + red[1] + red[2] + red[3];
  s2 = red[4] + red[5] + red[6] + red[7];
  const float m = s * (1.f / CA);
  const float var = s2 * (1.f / CA) - m * m;
  const float rs = rsqrtf(var + 1e-5f);
  #pragma unroll
  for (int i = 0; i < 3; ++i) {
    int c = tid + i * 256;
    an[(size_t)row * CA + c] = (x[i] - m) * rs * lnw[c] + lnb[c];
  }
}

// ---------------- K2: fused QKVG projection (fp32 SGEMM 128x128x8) ----------------
__global__ __launch_bounds__(256) void k2_qkvg(
    const float* __restrict__ an, const float* __restrict__ Wq,
    const float* __restrict__ Wk, const float* __restrict__ Wv,
    const float* __restrict__ Wg, const float* __restrict__ bq,
    short* __restrict__ qb, short* __restrict__ kb,
    short* __restrict__ vT, float* __restrict__ gbuf)
{
  const int bm = blockIdx.x & 7;
  const int bn = blockIdx.x >> 3;           // 0..23
  const int mat = bn / 6;                   // 0..3
  const int nc0 = (bn % 6) * 128;
  const float* __restrict__ W = (mat == 0) ? Wq : (mat == 1) ? Wk : (mat == 2) ? Wv : Wg;

  __shared__ __align__(16) float As[8][132];
  __shared__ __align__(16) float Bs[8][128];

  const int tid = threadIdx.x;
  const int tm = tid >> 4, tn = tid & 15;
  const int lrow = tid >> 1, lk4 = (tid & 1) * 4;
  const int brow = tid >> 5, bn4 = (tid & 31) * 4;
  const int m0 = bm * 128;

  float acc[2][2][4][4];
  #pragma unroll
  for (int p = 0; p < 2; ++p)
    #pragma unroll
    for (int r = 0; r < 2; ++r)
      #pragma unroll
      for (int i = 0; i < 4; ++i)
        #pragma unroll
        for (int j = 0; j < 4; ++j) acc[p][r][i][j] = 0.f;

  for (int k0 = 0; k0 < CA; k0 += 8) {
    v4f av = *(const v4f*)(an + (size_t)(m0 + lrow) * CA + k0 + lk4);
    v4f bv = *(const v4f*)(W + (size_t)(k0 + brow) * CA + nc0 + bn4);
    __syncthreads();
    As[lk4 + 0][lrow] = av[0]; As[lk4 + 1][lrow] = av[1];
    As[lk4 + 2][lrow] = av[2]; As[lk4 + 3][lrow] = av[3];
    *(v4f*)&Bs[brow][bn4] = bv;
    __syncthreads();
    #pragma unroll
    for (int kk = 0; kk < 8; ++kk) {
      v4f a0 = *(const v4f*)&As[kk][tm * 4];
      v4f a1 = *(const v4f*)&As[kk][64 + tm * 4];
      v4f b0 = *(const v4f*)&Bs[kk][tn * 4];
      v4f b1 = *(const v4f*)&Bs[kk][64 + tn * 4];
      #pragma unroll
      for (int i = 0; i < 4; ++i)
        #pragma unroll
        for (int j = 0; j < 4; ++j) {
          acc[0][0][i][j] += a0[i] * b0[j];
          acc[0][1][i][j] += a0[i] * b1[j];
          acc[1][0][i][j] += a1[i] * b0[j];
          acc[1][1][i][j] += a1[i] * b1[j];
        }
    }
  }

  #pragma unroll
  for (int p = 0; p < 2; ++p) {
    #pragma unroll
    for (int r = 0; r < 2; ++r) {
      const int mbase = m0 + p * 64 + tm * 4;
      const int cbase = nc0 + r * 64 + tn * 4;
      if (mat == 0) {
        #pragma unroll
        for (int i = 0; i < 4; ++i) {
          float v0 = (acc[p][r][i][0] + bq[cbase + 0]) * INV_SQRT_CH;
          float v1 = (acc[p][r][i][1] + bq[cbase + 1]) * INV_SQRT_CH;
          float v2 = (acc[p][r][i][2] + bq[cbase + 2]) * INV_SQRT_CH;
          float v3 = (acc[p][r][i][3] + bq[cbase + 3]) * INV_SQRT_CH;
          uint2 pk; pk.x = pack2(v0, v1); pk.y = pack2(v2, v3);
          *(uint2*)(qb + (size_t)(mbase + i) * HC + cbase) = pk;
        }
      } else if (mat == 1) {
        #pragma unroll
        for (int i = 0; i < 4; ++i) {
          uint2 pk;
          pk.x = pack2(acc[p][r][i][0], acc[p][r][i][1]);
          pk.y = pack2(acc[p][r][i][2], acc[p][r][i][3]);
          *(uint2*)(kb + (size_t)(mbase + i) * HC + cbase) = pk;
        }
      } else if (mat == 2) {
        #pragma unroll
        for (int j = 0; j < 4; ++j) {
          uint2 pk;
          pk.x = pack2(acc[p][r][0][j], acc[p][r][1][j]);
          pk.y = pack2(acc[p][r][2][j], acc[p][r][3][j]);
          *(uint2*)(vT + (size_t)(cbase + j) * NSEQ + mbase) = pk;
        }
      } else {
        #pragma unroll
        for (int i = 0; i < 4; ++i) {
          v4f g4;
          #pragma unroll
          for (int j = 0; j < 4; ++j)
            g4[j] = 1.f / (1.f + __expf(-acc[p][r][i][j]));
          *(v4f*)(gbuf + (size_t)(mbase + i) * HC + cbase) = g4;
        }
      }
    }
  }
}

// ---------------- K3: z-pass  LN(z)@Wb -> bpair[h][q][k] (bf16) ----------------
__global__ __launch_bounds__(256) void k3_zbias(
    const float* __restrict__ z, const short* __restrict__ wWp,
    const float* __restrict__ S1bW, short* __restrict__ bpair)
{
  const int q = blockIdx.x >> 4;
  const int k0 = (blockIdx.x & 15) << 6;
  const int tid = threadIdx.x;
  const int w = tid >> 6, l = tid & 63;
  const int r16 = l & 15, cg = l >> 4;

  __shared__ __align__(16) short blds[16 * 72];

  v8s bfrag[4];
  #pragma unroll
  for (int s = 0; s < 4; ++s) bfrag[s] = *(const v8s*)(wWp + (s * 64 + l) * 8);
  const float S1 = S1bW[r16];
  const float bW = S1bW[NH + r16];

  const int krow = k0 + w * 16 + r16;
  const float* __restrict__ zr = z + ((size_t)q * NSEQ + krow) * CZ;
  float sum = 0.f, sum2 = 0.f;
  v8s afrag[4];
  #pragma unroll
  for (int s = 0; s < 4; ++s) {
    v4f z0 = *(const v4f*)(zr + s * 32 + cg * 8);
    v4f z1 = *(const v4f*)(zr + s * 32 + cg * 8 + 4);
    v8s f;
    #pragma unroll
    for (int j = 0; j < 4; ++j) {
      sum += z0[j] + z1[j];
      sum2 += z0[j] * z0[j] + z1[j] * z1[j];
      f[j] = f2bf(z0[j]);
      f[j + 4] = f2bf(z1[j]);
    }
    afrag[s] = f;
  }
  sum  += __shfl_xor(sum, 16);  sum  += __shfl_xor(sum, 32);
  sum2 += __shfl_xor(sum2, 16); sum2 += __shfl_xor(sum2, 32);
  const float mean = sum * (1.f / CZ);
  const float var = sum2 * (1.f / CZ) - mean * mean;
  const float rs = rsqrtf(var + 1e-5f);

  v4f acc = {0.f, 0.f, 0.f, 0.f};
  #pragma unroll
  for (int s = 0; s < 4; ++s)
    acc = __builtin_amdgcn_mfma_f32_16x16x32_bf16(afrag[s], bfrag[s], acc, 0, 0, 0);

  #pragma unroll
  for (int j = 0; j < 4; ++j) {
    int src = cg * 4 + j;                 // lane that owns stats for C-row
    float mj = __shfl(mean, src);
    float rj = __shfl(rs, src);
    float bias = rj * (acc[j] - mj * S1) + bW;
    blds[r16 * 72 + w * 16 + cg * 4 + j] = f2bf(bias);
  }
  __syncthreads();
  const int h = tid >> 4, kk = (tid & 15) << 2;
  uint2 v = *(const uint2*)&blds[h * 72 + kk];
  *(uint2*)(bpair + (size_t)h * NSEQ * NSEQ + (size_t)q * NSEQ + k0 + kk) = v;
}

// ---------------- K4: flash attention (MFMA bf16) -> go = g * softmax(QK^T+bias) V ----------------
__global__ __launch_bounds__(256) void k4_attn(
    const short* __restrict__ qb, const short* __restrict__ kb,
    const short* __restrict__ vT, const short* __restrict__ bpair,
    const float* __restrict__ mask, const float* __restrict__ gbuf,
    float* __restrict__ go)
{
  const int h = blockIdx.x & 15;
  const int qt = blockIdx.x >> 4;
  const int tid = threadIdx.x;
  const int w = tid >> 6, l = tid & 63;
  const int r16 = l & 15, cg = l >> 4;
  const int q0 = qt * 64 + w * 16;

  __shared__ __align__(16) short plds[4][16 * 40];
  short* pl = &plds[w][0];

  const v8s vzero = {0, 0, 0, 0, 0, 0, 0, 0};
  v8s qf0, qf1;
  {
    const short* qp = qb + (size_t)(q0 + r16) * HC + h * CHD;
    qf0 = *(const v8s*)(qp + cg * 8);
    qf1 = (cg < 2) ? *(const v8s*)(qp + 32 + cg * 8) : vzero;
  }
  v4f of0 = {0, 0, 0, 0}, of1 = {0, 0, 0, 0}, of2 = {0, 0, 0, 0};
  float mrun[4], lrun[4];
  #pragma unroll
  for (int j = 0; j < 4; ++j) { mrun[j] = -1e30f; lrun[j] = 0.f; }

  const size_t bpb = (size_t)h * NSEQ * NSEQ;

  for (int k0 = 0; k0 < NSEQ; k0 += 32) {
    v4f cs0 = {0, 0, 0, 0}, cs1 = {0, 0, 0, 0};
    {
      const short* kp = kb + (size_t)(k0 + r16) * HC + h * CHD;
      v8s b0 = *(const v8s*)(kp + cg * 8);
      v8s b1 = (cg < 2) ? *(const v8s*)(kp + 32 + cg * 8) : vzero;
      cs0 = __builtin_amdgcn_mfma_f32_16x16x32_bf16(qf0, b0, cs0, 0, 0, 0);
      cs0 = __builtin_amdgcn_mfma_f32_16x16x32_bf16(qf1, b1, cs0, 0, 0, 0);
    }
    {
      const short* kp = kb + (size_t)(k0 + 16 + r16) * HC + h * CHD;
      v8s b0 = *(const v8s*)(kp + cg * 8);
      v8s b1 = (cg < 2) ? *(const v8s*)(kp + 32 + cg * 8) : vzero;
      cs1 = __builtin_amdgcn_mfma_f32_16x16x32_bf16(qf0, b0, cs1, 0, 0, 0);
      cs1 = __builtin_amdgcn_mfma_f32_16x16x32_bf16(qf1, b1, cs1, 0, 0, 0);
    }
    float sv0[4], sv1[4];
    {
      const int kc0 = k0 + r16, kc1 = k0 + 16 + r16;
      const float mb0 = (mask[kc0] - 1.f) * 1e9f;
      const float mb1 = (mask[kc1] - 1.f) * 1e9f;
      #pragma unroll
      for (int j = 0; j < 4; ++j) {
        size_t qo = bpb + (size_t)(q0 + cg * 4 + j) * NSEQ;
        sv0[j] = cs0[j] + bf2f(bpair[qo + kc0]) + mb0;
        sv1[j] = cs1[j] + bf2f(bpair[qo + kc1]) + mb1;
      }
    }
    #pragma unroll
    for (int j = 0; j < 4; ++j) {
      float mx = fmaxf(sv0[j], sv1[j]);
      mx = fmaxf(mx, __shfl_xor(mx, 1));
      mx = fmaxf(mx, __shfl_xor(mx, 2));
      mx = fmaxf(mx, __shfl_xor(mx, 4));
      mx = fmaxf(mx, __shfl_xor(mx, 8));
      float mnew = fmaxf(mrun[j], mx);
      float alpha = __expf(mrun[j] - mnew);
      mrun[j] = mnew;
      float p0 = __expf(sv0[j] - mnew);
      float p1 = __expf(sv1[j] - mnew);
      float rsum = p0 + p1;
      rsum += __shfl_xor(rsum, 1);
      rsum += __shfl_xor(rsum, 2);
      rsum += __shfl_xor(rsum, 4);
      rsum += __shfl_xor(rsum, 8);
      lrun[j] = lrun[j] * alpha + rsum;
      of0[j] *= alpha; of1[j] *= alpha; of2[j] *= alpha;
      const int rr = (cg * 4 + j) * 40;
      pl[rr + r16] = f2bf(p0);
      pl[rr + 16 + r16] = f2bf(p1);
    }
    asm volatile("s_waitcnt lgkmcnt(0)" ::: "memory");
    __builtin_amdgcn_sched_barrier(0);
    v8s pa = *(const v8s*)(pl + r16 * 40 + cg * 8);
    {
      const short* vp = vT + (size_t)(h * CHD + r16) * NSEQ + k0 + cg * 8;
      v8s bv0 = *(const v8s*)vp;
      v8s bv1 = *(const v8s*)(vp + 16 * NSEQ);
      v8s bv2 = *(const v8s*)(vp + 32 * NSEQ);
      of0 = __builtin_amdgcn_mfma_f32_16x16x32_bf16(pa, bv0, of0, 0, 0, 0);
      of1 = __builtin_amdgcn_mfma_f32_16x16x32_bf16(pa, bv1, of1, 0, 0, 0);
      of2 = __builtin_amdgcn_mfma_f32_16x16x32_bf16(pa, bv2, of2, 0, 0, 0);
    }
  }
  #pragma unroll
  for (int j = 0; j < 4; ++j) {
    const int qrow = q0 + cg * 4 + j;
    const float inv = 1.f / lrun[j];
    const size_t rb = (size_t)qrow * HC + h * CHD + r16;
    go[rb]      = of0[j] * inv * gbuf[rb];
    go[rb + 16] = of1[j] * inv * gbuf[rb + 16];
    go[rb + 32] = of2[j] * inv * gbuf[rb + 32];
  }
}

// ---------------- K5: out = go @ Wo (fp32 SGEMM 64x64x16) ----------------
__global__ __launch_bounds__(256) void k5_out(
    const float* __restrict__ go, const float* __restrict__ Wo,
    float* __restrict__ out)
{
  const int bm = blockIdx.x & 15;
  const int bn = blockIdx.x >> 4;
  __shared__ __align__(16) float As[16][68];
  __shared__ __align__(16) float Bs[16][64];
  const int tid = threadIdx.x;
  const int tm = tid >> 4, tn = tid & 15;
  const int lrow = tid >> 2, lk4 = (tid & 3) * 4;
  const int brow = tid >> 4, bn4 = (tid & 15) * 4;
  float acc[4][4];
  #pragma unroll
  for (int i = 0; i < 4; ++i)
    #pragma unroll
    for (int j = 0; j < 4; ++j) acc[i][j] = 0.f;

  for (int k0 = 0; k0 < CA; k0 += 16) {
    v4f av = *(const v4f*)(go + (size_t)(bm * 64 + lrow) * CA + k0 + lk4);
    v4f bv = *(const v4f*)(Wo + (size_t)(k0 + brow) * CA + bn * 64 + bn4);
    __syncthreads();
    As[lk4 + 0][lrow] = av[0]; As[lk4 + 1][lrow] = av[1];
    As[lk4 + 2][lrow] = av[2]; As[lk4 + 3][lrow] = av[3];
    *(v4f*)&Bs[brow][bn4] = bv;
    __syncthreads();
    #pragma unroll
    for (int kk = 0; kk < 16; ++kk) {
      v4f a = *(const v4f*)&As[kk][tm * 4];
      v4f b = *(const v4f*)&Bs[kk][tn * 4];
      #pragma unroll
      for (int i = 0; i < 4; ++i)
        #pragma unroll
        for (int j = 0; j < 4; ++j) acc[i][j] += a[i] * b[j];
    }
  }
  #pragma unroll
  for (int i = 0; i < 4; ++i) {
    v4f o;
    #pragma unroll
    for (int j = 0; j < 4; ++j) o[j] = acc[i][j];
    *(v4f*)(out + (size_t)(bm * 64 + tm * 4 + i) * CA + bn * 64 + tn * 4) = o;
  }
}

extern "C" void kernel_launch(void* const* d_in, const int* in_sizes, int n_in,
                              void* d_out, int out_size, void* d_ws, size_t ws_size,
                              hipStream_t stream) {
  const float* a      = (const float*)d_in[0];
  const float* z      = (const float*)d_in[1];
  const float* mask   = (const float*)d_in[2];
  const float* ln_a_w = (const float*)d_in[3];
  const float* ln_a_b = (const float*)d_in[4];
  const float* ln_z_w = (const float*)d_in[5];
  const float* ln_z_b = (const float*)d_in[6];
  const float* Wq     = (const float*)d_in[7];
  const float* bq     = (const float*)d_in[8];
  const float* Wk     = (const float*)d_in[9];
  const float* Wv     = (const float*)d_in[10];
  const float* Wb     = (const float*)d_in[11];
  const float* Wg     = (const float*)d_in[12];
  const float* Wo     = (const float*)d_in[13];
  float* out = (float*)d_out;

  char* ws = (char*)d_ws;
  float* an    = (float*)(ws);                               // 3 MB
  float* gbuf  = (float*)(ws + (3ull << 20));                // 3 MB
  float* go    = (float*)(ws + (6ull << 20));                // 3 MB
  short* qb    = (short*)(ws + (9ull << 20));                // 1.5 MB
  short* kb    = (short*)(ws + (9ull << 20) + 1572864ull);   // 1.5 MB
  short* vT    = (short*)(ws + (9ull << 20) + 3145728ull);   // 1.5 MB
  short* wWp   = (short*)(ws + (14ull << 20));               // 4 KB
  float* S1bW  = (float*)(ws + (14ull << 20) + 4096ull);     // 128 B
  short* bpair = (short*)(ws + (16ull << 20));               // 32 MB

  k0_prep<<<1, 256, 0, stream>>>(ln_z_w, ln_z_b, Wb, wWp, S1bW);
  k1_ln_a<<<1024, 256, 0, stream>>>(a, ln_a_w, ln_a_b, an);
  k2_qkvg<<<192, 256, 0, stream>>>(an, Wq, Wk, Wv, Wg, bq, qb, kb, vT, gbuf);
  k3_zbias<<<16384, 256, 0, stream>>>(z, wWp, S1bW, bpair);
  k4_attn<<<256, 256, 0, stream>>>(qb, kb, vT, bpair, mask, gbuf, go);
  k5_out<<<192, 256, 0, stream>>>(go, Wo, out);
}

// Round 2
// 268.282 us; speedup vs baseline: 1.4370x; 1.4370x over previous
//
#include <hip/hip_runtime.h>

#define NSEQ 1024
#define CA   768
#define CZ   128
#define NH   16
#define CHD  48
#define HC   768
#define INV_SQRT_CH 0.14433756729740643f

typedef float v4f __attribute__((ext_vector_type(4)));
typedef short v8s __attribute__((ext_vector_type(8)));

__device__ __forceinline__ short f2bf(float f) {
  union { float f; unsigned u; } v; v.f = f;
  unsigned r = v.u + 0x7fffu + ((v.u >> 16) & 1u);
  return (short)(r >> 16);
}
__device__ __forceinline__ float bf2f(short s) {
  union { unsigned u; float f; } v;
  v.u = ((unsigned)(unsigned short)s) << 16;
  return v.f;
}
__device__ __forceinline__ unsigned pack2(float a, float b) {
  return (unsigned)(unsigned short)f2bf(a) |
         ((unsigned)(unsigned short)f2bf(b) << 16);
}

// ---------------- K0: precompute wW fragments + S1/bW for z-pass ----------------
__global__ __launch_bounds__(256) void k0_prep(
    const float* __restrict__ lnw, const float* __restrict__ lnb,
    const float* __restrict__ Wb, short* __restrict__ wWp,
    float* __restrict__ S1bW)
{
  const int t = threadIdx.x;
  const int s = t >> 6, l = t & 63;
  const int r16 = l & 15, cg = l >> 4;
  float v[8];
  #pragma unroll
  for (int j = 0; j < 8; ++j) {
    int d = s * 32 + cg * 8 + j;
    v[j] = lnw[d] * Wb[d * NH + r16];
  }
  uint4 pk;
  pk.x = pack2(v[0], v[1]); pk.y = pack2(v[2], v[3]);
  pk.z = pack2(v[4], v[5]); pk.w = pack2(v[6], v[7]);
  *(uint4*)(wWp + (s * 64 + l) * 8) = pk;
  if (t < NH) {
    float s1 = 0.f, bw = 0.f;
    for (int d = 0; d < CZ; ++d) {
      float wb = Wb[d * NH + t];
      s1 += bf2f(f2bf(lnw[d] * wb));
      bw += lnb[d] * wb;
    }
    S1bW[t] = s1;
    S1bW[NH + t] = bw;
  }
}

// ---------------- KC: transpose+convert [Wq*s|Wk|Wv|Wg] -> WT[3072][768] bf16 ----------------
__global__ __launch_bounds__(256) void kc_conv(
    const float* __restrict__ Wq, const float* __restrict__ Wk,
    const float* __restrict__ Wv, const float* __restrict__ Wg,
    short* __restrict__ WT)
{
  __shared__ float tile[64][65];
  const int bid = blockIdx.x;
  const int mat = bid / 144, rem = bid % 144;
  const int tk = rem % 12, tn = rem / 12;
  const int k0 = tk * 64, n0 = tn * 64;
  const float* __restrict__ W = (mat == 0) ? Wq : (mat == 1) ? Wk : (mat == 2) ? Wv : Wg;
  const float s = (mat == 0) ? INV_SQRT_CH : 1.f;
  const int t = threadIdx.x;
  const int rr = t >> 4, cc = (t & 15) * 4;
  #pragma unroll
  for (int r = 0; r < 4; ++r) {
    v4f v = *(const v4f*)(W + (size_t)(k0 + r * 16 + rr) * HC + n0 + cc);
    tile[r * 16 + rr][cc + 0] = v[0];
    tile[r * 16 + rr][cc + 1] = v[1];
    tile[r * 16 + rr][cc + 2] = v[2];
    tile[r * 16 + rr][cc + 3] = v[3];
  }
  __syncthreads();
  #pragma unroll
  for (int r = 0; r < 4; ++r) {
    const int nr = r * 16 + rr;
    float t0 = tile[cc + 0][nr] * s;
    float t1 = tile[cc + 1][nr] * s;
    float t2 = tile[cc + 2][nr] * s;
    float t3 = tile[cc + 3][nr] * s;
    uint2 pk; pk.x = pack2(t0, t1); pk.y = pack2(t2, t3);
    *(uint2*)(WT + (size_t)(mat * HC + n0 + nr) * HC + k0 + cc) = pk;
  }
}

// ---------------- K1: LayerNorm(a) -> anb (bf16) ----------------
__global__ __launch_bounds__(256) void k1_ln_a(
    const float* __restrict__ a, const float* __restrict__ lnw,
    const float* __restrict__ lnb, short* __restrict__ anb)
{
  const int row = blockIdx.x;
  const int tid = threadIdx.x;
  const float* ar = a + (size_t)row * CA;
  float x[3];
  float s = 0.f, s2 = 0.f;
  #pragma unroll
  for (int i = 0; i < 3; ++i) {
    x[i] = ar[tid + i * 256];
    s += x[i]; s2 += x[i] * x[i];
  }
  #pragma unroll
  for (int off = 1; off < 64; off <<= 1) {
    s += __shfl_xor(s, off);
    s2 += __shfl_xor(s2, off);
  }
  __shared__ float red[8];
  const int wv = tid >> 6;
  if ((tid & 63) == 0) { red[wv] = s; red[4 + wv] = s2; }
  __syncthreads();
  s = red[0] + red[1] + red[2] + red[3];
  s2 = red[4] + red[5] + red[6] + red[7];
  const float m = s * (1.f / CA);
  const float var = s2 * (1.f / CA) - m * m;
  const float rs = rsqrtf(var + 1e-5f);
  #pragma unroll
  for (int i = 0; i < 3; ++i) {
    int c = tid + i * 256;
    anb[(size_t)row * CA + c] = f2bf((x[i] - m) * rs * lnw[c] + lnb[c]);
  }
}

// ---------------- K23: fused {QKVG MFMA GEMM (blocks 0..191)} + {z-bias pass} ----------------
__global__ __launch_bounds__(256) void k23_fused(
    const short* __restrict__ anb, const short* __restrict__ WT,
    const float* __restrict__ bq, const float* __restrict__ z,
    const short* __restrict__ wWp, const float* __restrict__ S1bW,
    short* __restrict__ qb, short* __restrict__ kb, short* __restrict__ vT,
    float* __restrict__ gbuf, short* __restrict__ bpair)
{
  __shared__ __align__(16) char smem[20480];
  const int tid = threadIdx.x;
  const int w = tid >> 6, l = tid & 63;
  const int r16 = l & 15, cg = l >> 4;

  if (blockIdx.x < 192) {
    // ---------- bf16 MFMA GEMM: C[1024][3072] = anb @ WT^T ----------
    const int bid = blockIdx.x;
    const int bm = bid & 7;
    const int bnb = bid >> 3;            // 0..23
    const int m0 = bm * 128, n0 = bnb * 128;
    const int wr = w >> 1, wc = w & 1;

    short* As = (short*)smem;            // [128][40] (stride 40, cols 0..31 used)
    short* Bs = (short*)(smem + 10240);  // [128][40]

    const int strow = w * 16 + (l >> 2); // 0..63
    const int scol = (l & 3) * 8;        // 0,8,16,24

    v4f acc[4][4];
    #pragma unroll
    for (int i = 0; i < 4; ++i)
      #pragma unroll
      for (int j = 0; j < 4; ++j)
        acc[i][j] = (v4f){0.f, 0.f, 0.f, 0.f};

    for (int k0 = 0; k0 < CA; k0 += 32) {
      v8s av0 = *(const v8s*)(anb + (size_t)(m0 + strow) * CA + k0 + scol);
      v8s av1 = *(const v8s*)(anb + (size_t)(m0 + 64 + strow) * CA + k0 + scol);
      v8s bv0 = *(const v8s*)(WT + (size_t)(n0 + strow) * CA + k0 + scol);
      v8s bv1 = *(const v8s*)(WT + (size_t)(n0 + 64 + strow) * CA + k0 + scol);
      __syncthreads();
      *(v8s*)(As + (size_t)strow * 40 + scol) = av0;
      *(v8s*)(As + (size_t)(64 + strow) * 40 + scol) = av1;
      *(v8s*)(Bs + (size_t)strow * 40 + scol) = bv0;
      *(v8s*)(Bs + (size_t)(64 + strow) * 40 + scol) = bv1;
      __syncthreads();
      v8s a[4], b[4];
      #pragma unroll
      for (int m = 0; m < 4; ++m)
        a[m] = *(const v8s*)(As + (wr * 64 + m * 16 + r16) * 40 + cg * 8);
      #pragma unroll
      for (int n = 0; n < 4; ++n)
        b[n] = *(const v8s*)(Bs + (wc * 64 + n * 16 + r16) * 40 + cg * 8);
      #pragma unroll
      for (int m = 0; m < 4; ++m)
        #pragma unroll
        for (int n = 0; n < 4; ++n)
          acc[m][n] = __builtin_amdgcn_mfma_f32_16x16x32_bf16(a[m], b[n], acc[m][n], 0, 0, 0);
    }

    const int matsel = n0 / HC;
    #pragma unroll
    for (int n = 0; n < 4; ++n) {
      const int nc = (n0 % HC) + wc * 64 + n * 16 + r16;   // col within matrix
      const int rbase = m0 + wr * 64 + cg * 4;             // + m*16 + j
      if (matsel == 0) {
        const float bqs = bq[nc] * INV_SQRT_CH;
        #pragma unroll
        for (int m = 0; m < 4; ++m)
          #pragma unroll
          for (int j = 0; j < 4; ++j)
            qb[(size_t)(rbase + m * 16 + j) * HC + nc] = f2bf(acc[m][n][j] + bqs);
      } else if (matsel == 1) {
        #pragma unroll
        for (int m = 0; m < 4; ++m)
          #pragma unroll
          for (int j = 0; j < 4; ++j)
            kb[(size_t)(rbase + m * 16 + j) * HC + nc] = f2bf(acc[m][n][j]);
      } else if (matsel == 2) {
        #pragma unroll
        for (int m = 0; m < 4; ++m) {
          uint2 pk;
          pk.x = pack2(acc[m][n][0], acc[m][n][1]);
          pk.y = pack2(acc[m][n][2], acc[m][n][3]);
          *(uint2*)(vT + (size_t)nc * NSEQ + rbase + m * 16) = pk;
        }
      } else {
        #pragma unroll
        for (int m = 0; m < 4; ++m)
          #pragma unroll
          for (int j = 0; j < 4; ++j)
            gbuf[(size_t)(rbase + m * 16 + j) * HC + nc] =
                1.f / (1.f + __expf(-acc[m][n][j]));
      }
    }
  } else {
    // ---------- z-bias: LN(z)@Wb -> bpair[h][q][k] ----------
    const int zbid = blockIdx.x - 192;
    const int q = zbid >> 4;
    const int k0 = (zbid & 15) << 6;
    short* blds = (short*)smem;          // [16][72]

    v8s bfrag[4];
    #pragma unroll
    for (int s = 0; s < 4; ++s) bfrag[s] = *(const v8s*)(wWp + (s * 64 + l) * 8);
    const float S1 = S1bW[r16];
    const float bW = S1bW[NH + r16];

    const int krow = k0 + w * 16 + r16;
    const float* __restrict__ zr = z + ((size_t)q * NSEQ + krow) * CZ;
    float sum = 0.f, sum2 = 0.f;
    v8s afrag[4];
    #pragma unroll
    for (int s = 0; s < 4; ++s) {
      v4f z0 = *(const v4f*)(zr + s * 32 + cg * 8);
      v4f z1 = *(const v4f*)(zr + s * 32 + cg * 8 + 4);
      v8s f;
      #pragma unroll
      for (int j = 0; j < 4; ++j) {
        sum += z0[j] + z1[j];
        sum2 += z0[j] * z0[j] + z1[j] * z1[j];
        f[j] = f2bf(z0[j]);
        f[j + 4] = f2bf(z1[j]);
      }
      afrag[s] = f;
    }
    sum  += __shfl_xor(sum, 16);  sum  += __shfl_xor(sum, 32);
    sum2 += __shfl_xor(sum2, 16); sum2 += __shfl_xor(sum2, 32);
    const float mean = sum * (1.f / CZ);
    const float var = sum2 * (1.f / CZ) - mean * mean;
    const float rs = rsqrtf(var + 1e-5f);

    v4f acc = {0.f, 0.f, 0.f, 0.f};
    #pragma unroll
    for (int s = 0; s < 4; ++s)
      acc = __builtin_amdgcn_mfma_f32_16x16x32_bf16(afrag[s], bfrag[s], acc, 0, 0, 0);

    #pragma unroll
    for (int j = 0; j < 4; ++j) {
      int src = cg * 4 + j;
      float mj = __shfl(mean, src);
      float rj = __shfl(rs, src);
      float bias = rj * (acc[j] - mj * S1) + bW;
      blds[r16 * 72 + w * 16 + cg * 4 + j] = f2bf(bias);
    }
    __syncthreads();
    const int h = tid >> 4, kk = (tid & 15) << 2;
    uint2 v = *(const uint2*)&blds[h * 72 + kk];
    *(uint2*)(bpair + (size_t)h * NSEQ * NSEQ + (size_t)q * NSEQ + k0 + kk) = v;
  }
}

// ---------------- K4: flash attention (MFMA bf16) -> go = g * softmax(QK^T+bias) V ----------------
__global__ __launch_bounds__(256) void k4_attn(
    const short* __restrict__ qb, const short* __restrict__ kb,
    const short* __restrict__ vT, const short* __restrict__ bpair,
    const float* __restrict__ mask, const float* __restrict__ gbuf,
    float* __restrict__ go)
{
  const int h = blockIdx.x & 15;
  const int qt = blockIdx.x >> 4;
  const int tid = threadIdx.x;
  const int w = tid >> 6, l = tid & 63;
  const int r16 = l & 15, cg = l >> 4;
  const int q0 = qt * 64 + w * 16;

  __shared__ __align__(16) short plds[4][16 * 40];
  short* pl = &plds[w][0];

  const v8s vzero = {0, 0, 0, 0, 0, 0, 0, 0};
  v8s qf0, qf1;
  {
    const short* qp = qb + (size_t)(q0 + r16) * HC + h * CHD;
    qf0 = *(const v8s*)(qp + cg * 8);
    qf1 = (cg < 2) ? *(const v8s*)(qp + 32 + cg * 8) : vzero;
  }
  v4f of0 = {0, 0, 0, 0}, of1 = {0, 0, 0, 0}, of2 = {0, 0, 0, 0};
  float mrun[4], lrun[4];
  #pragma unroll
  for (int j = 0; j < 4; ++j) { mrun[j] = -1e30f; lrun[j] = 0.f; }

  const size_t bpb = (size_t)h * NSEQ * NSEQ;

  for (int k0 = 0; k0 < NSEQ; k0 += 32) {
    v4f cs0 = {0, 0, 0, 0}, cs1 = {0, 0, 0, 0};
    {
      const short* kp = kb + (size_t)(k0 + r16) * HC + h * CHD;
      v8s b0 = *(const v8s*)(kp + cg * 8);
      v8s b1 = (cg < 2) ? *(const v8s*)(kp + 32 + cg * 8) : vzero;
      cs0 = __builtin_amdgcn_mfma_f32_16x16x32_bf16(qf0, b0, cs0, 0, 0, 0);
      cs0 = __builtin_amdgcn_mfma_f32_16x16x32_bf16(qf1, b1, cs0, 0, 0, 0);
    }
    {
      const short* kp = kb + (size_t)(k0 + 16 + r16) * HC + h * CHD;
      v8s b0 = *(const v8s*)(kp + cg * 8);
      v8s b1 = (cg < 2) ? *(const v8s*)(kp + 32 + cg * 8) : vzero;
      cs1 = __builtin_amdgcn_mfma_f32_16x16x32_bf16(qf0, b0, cs1, 0, 0, 0);
      cs1 = __builtin_amdgcn_mfma_f32_16x16x32_bf16(qf1, b1, cs1, 0, 0, 0);
    }
    float sv0[4], sv1[4];
    {
      const int kc0 = k0 + r16, kc1 = k0 + 16 + r16;
      const float mb0 = (mask[kc0] - 1.f) * 1e9f;
      const float mb1 = (mask[kc1] - 1.f) * 1e9f;
      #pragma unroll
      for (int j = 0; j < 4; ++j) {
        size_t qo = bpb + (size_t)(q0 + cg * 4 + j) * NSEQ;
        sv0[j] = cs0[j] + bf2f(bpair[qo + kc0]) + mb0;
        sv1[j] = cs1[j] + bf2f(bpair[qo + kc1]) + mb1;
      }
    }
    #pragma unroll
    for (int j = 0; j < 4; ++j) {
      float mx = fmaxf(sv0[j], sv1[j]);
      mx = fmaxf(mx, __shfl_xor(mx, 1));
      mx = fmaxf(mx, __shfl_xor(mx, 2));
      mx = fmaxf(mx, __shfl_xor(mx, 4));
      mx = fmaxf(mx, __shfl_xor(mx, 8));
      float mnew = fmaxf(mrun[j], mx);
      float alpha = __expf(mrun[j] - mnew);
      mrun[j] = mnew;
      float p0 = __expf(sv0[j] - mnew);
      float p1 = __expf(sv1[j] - mnew);
      float rsum = p0 + p1;
      rsum += __shfl_xor(rsum, 1);
      rsum += __shfl_xor(rsum, 2);
      rsum += __shfl_xor(rsum, 4);
      rsum += __shfl_xor(rsum, 8);
      lrun[j] = lrun[j] * alpha + rsum;
      of0[j] *= alpha; of1[j] *= alpha; of2[j] *= alpha;
      const int rr = (cg * 4 + j) * 40;
      pl[rr + r16] = f2bf(p0);
      pl[rr + 16 + r16] = f2bf(p1);
    }
    asm volatile("s_waitcnt lgkmcnt(0)" ::: "memory");
    __builtin_amdgcn_sched_barrier(0);
    v8s pa = *(const v8s*)(pl + r16 * 40 + cg * 8);
    {
      const short* vp = vT + (size_t)(h * CHD + r16) * NSEQ + k0 + cg * 8;
      v8s bv0 = *(const v8s*)vp;
      v8s bv1 = *(const v8s*)(vp + 16 * NSEQ);
      v8s bv2 = *(const v8s*)(vp + 32 * NSEQ);
      of0 = __builtin_amdgcn_mfma_f32_16x16x32_bf16(pa, bv0, of0, 0, 0, 0);
      of1 = __builtin_amdgcn_mfma_f32_16x16x32_bf16(pa, bv1, of1, 0, 0, 0);
      of2 = __builtin_amdgcn_mfma_f32_16x16x32_bf16(pa, bv2, of2, 0, 0, 0);
    }
  }
  #pragma unroll
  for (int j = 0; j < 4; ++j) {
    const int qrow = q0 + cg * 4 + j;
    const float inv = 1.f / lrun[j];
    const size_t rb = (size_t)qrow * HC + h * CHD + r16;
    go[rb]      = of0[j] * inv * gbuf[rb];
    go[rb + 16] = of1[j] * inv * gbuf[rb + 16];
    go[rb + 32] = of2[j] * inv * gbuf[rb + 32];
  }
}

// ---------------- K5: out = go @ Wo (fp32 SGEMM 64x64x16) ----------------
__global__ __launch_bounds__(256) void k5_out(
    const float* __restrict__ go, const float* __restrict__ Wo,
    float* __restrict__ out)
{
  const int bm = blockIdx.x & 15;
  const int bn = blockIdx.x >> 4;
  __shared__ __align__(16) float As[16][68];
  __shared__ __align__(16) float Bs[16][64];
  const int tid = threadIdx.x;
  const int tm = tid >> 4, tn = tid & 15;
  const int lrow = tid >> 2, lk4 = (tid & 3) * 4;
  const int brow = tid >> 4, bn4 = (tid & 15) * 4;
  float acc[4][4];
  #pragma unroll
  for (int i = 0; i < 4; ++i)
    #pragma unroll
    for (int j = 0; j < 4; ++j) acc[i][j] = 0.f;

  for (int k0 = 0; k0 < CA; k0 += 16) {
    v4f av = *(const v4f*)(go + (size_t)(bm * 64 + lrow) * CA + k0 + lk4);
    v4f bv = *(const v4f*)(Wo + (size_t)(k0 + brow) * CA + bn * 64 + bn4);
    __syncthreads();
    As[lk4 + 0][lrow] = av[0]; As[lk4 + 1][lrow] = av[1];
    As[lk4 + 2][lrow] = av[2]; As[lk4 + 3][lrow] = av[3];
    *(v4f*)&Bs[brow][bn4] = bv;
    __syncthreads();
    #pragma unroll
    for (int kk = 0; kk < 16; ++kk) {
      v4f a = *(const v4f*)&As[kk][tm * 4];
      v4f b = *(const v4f*)&Bs[kk][tn * 4];
      #pragma unroll
      for (int i = 0; i < 4; ++i)
        #pragma unroll
        for (int j = 0; j < 4; ++j) acc[i][j] += a[i] * b[j];
    }
  }
  #pragma unroll
  for (int i = 0; i < 4; ++i) {
    v4f o;
    #pragma unroll
    for (int j = 0; j < 4; ++j) o[j] = acc[i][j];
    *(v4f*)(out + (size_t)(bm * 64 + tm * 4 + i) * CA + bn * 64 + tn * 4) = o;
  }
}

extern "C" void kernel_launch(void* const* d_in, const int* in_sizes, int n_in,
                              void* d_out, int out_size, void* d_ws, size_t ws_size,
                              hipStream_t stream) {
  const float* a      = (const float*)d_in[0];
  const float* z      = (const float*)d_in[1];
  const float* mask   = (const float*)d_in[2];
  const float* ln_a_w = (const float*)d_in[3];
  const float* ln_a_b = (const float*)d_in[4];
  const float* ln_z_w = (const float*)d_in[5];
  const float* ln_z_b = (const float*)d_in[6];
  const float* Wq     = (const float*)d_in[7];
  const float* bq     = (const float*)d_in[8];
  const float* Wk     = (const float*)d_in[9];
  const float* Wv     = (const float*)d_in[10];
  const float* Wb     = (const float*)d_in[11];
  const float* Wg     = (const float*)d_in[12];
  const float* Wo     = (const float*)d_in[13];
  float* out = (float*)d_out;

  char* ws = (char*)d_ws;
  short* anb   = (short*)(ws);                               // 1.5 MB
  short* WT    = (short*)(ws + (2ull << 20));                // 4.5 MB
  short* qb    = (short*)(ws + (7ull << 20));                // 1.5 MB
  short* kb    = (short*)(ws + (9ull << 20));                // 1.5 MB
  short* vT    = (short*)(ws + (11ull << 20));               // 1.5 MB
  float* gbuf  = (float*)(ws + (13ull << 20));               // 3 MB
  float* go    = (float*)(ws + (17ull << 20));               // 3 MB
  short* wWp   = (short*)(ws + (21ull << 20));               // 4 KB
  float* S1bW  = (float*)(ws + (21ull << 20) + 4096ull);     // 128 B
  short* bpair = (short*)(ws + (22ull << 20));               // 32 MB

  k0_prep<<<1, 256, 0, stream>>>(ln_z_w, ln_z_b, Wb, wWp, S1bW);
  kc_conv<<<576, 256, 0, stream>>>(Wq, Wk, Wv, Wg, WT);
  k1_ln_a<<<1024, 256, 0, stream>>>(a, ln_a_w, ln_a_b, anb);
  k23_fused<<<192 + 16384, 256, 0, stream>>>(anb, WT, bq, z, wWp, S1bW,
                                             qb, kb, vT, gbuf, bpair);
  k4_attn<<<256, 256, 0, stream>>>(qb, kb, vT, bpair, mask, gbuf, go);
  k5_out<<<192, 256, 0, stream>>>(go, Wo, out);
}